// Round 1
// baseline (1720.700 us; speedup 1.0000x reference)
//
#include <hip/hip_runtime.h>

// Problem dims (fixed)
#define HID_   128
#define BB_    256
#define TT_    300
#define DIN_   700
#define LL_    4
#define NOUT_  20

// d_out layout (floats): out[256*20] | hid4_mem[256*301*128] | hid4_spk[...] | A_norm[1]
#define OUT_OFF   0
#define HMEM_OFF  5120
#define HSPK_OFF  (5120 + 256*301*128)            // 9,868,288
#define ANORM_OFF (5120 + 2*256*301*128)          // 19,731,456

// ws layout (floats): inp[76800*128] | rates[4*256*128]
#define WS_INP_OFF   0
#define WS_RATES_OFF (76800*128)

// ---------------------------------------------------------------------------
// K1: inp[r][h] = sum_d x[r][d] * w_in[d][h] + b_in[h],   r = b*300 + t
// block = 128 threads (h), 16 rows per block. w-chunk (70) register resident,
// x values are wave-uniform -> scalar loads. Pure VALU inner loop.
// ---------------------------------------------------------------------------
__global__ __launch_bounds__(128, 4)
void k1_in_proj(const float* __restrict__ x, const float* __restrict__ w,
                const float* __restrict__ bin, float* __restrict__ inp)
{
    const int h = threadIdx.x;
    const long r0 = (long)blockIdx.x * 16;

    float acc[16];
    const float bv = bin[h];
#pragma unroll
    for (int r = 0; r < 16; ++r) acc[r] = bv;

    // 10 chunks of 70 (700 = 10*70, no tail)
    for (int kc = 0; kc < 10; ++kc) {
        const int k0 = kc * 70;
        float wreg[70];
#pragma unroll
        for (int j = 0; j < 70; ++j) wreg[j] = w[(long)(k0 + j) * 128 + h];

#pragma unroll
        for (int r = 0; r < 16; ++r) {
            const float* __restrict__ xr = x + (r0 + r) * (long)DIN_ + k0;
#pragma unroll
            for (int j = 0; j < 70; ++j)
                acc[r] = fmaf(xr[j], wreg[j], acc[r]);
        }
    }

#pragma unroll
    for (int r = 0; r < 16; ++r)
        inp[(r0 + r) * (long)HID_ + h] = acc[r];
}

// ---------------------------------------------------------------------------
// K3: fused reservoir drive + scan.  block = (l,b) pair (bid = b*4 + l),
// thread = output neuron h. A_w column held in 128 VGPRs; inp[b,t,:] read as
// wave-uniform scalars. Writes hid4 mem/spk (l==3) and spike rates.
// ---------------------------------------------------------------------------
__global__ __launch_bounds__(128, 2)
void k3_scan(const float* __restrict__ inp, const float* __restrict__ Aw,
             const float* __restrict__ Ab, const float* __restrict__ thr,
             const float* __restrict__ dec, const float* __restrict__ rstv,
             const float* __restrict__ mem0, float* __restrict__ rates,
             float* __restrict__ omem, float* __restrict__ ospk)
{
    const int h = threadIdx.x;
    const int bid = blockIdx.x;
    const int l = bid & 3;
    const int b = bid >> 2;

    // A column: a[k] = A_w[l][k][h]  (contraction over k)
    float a[128];
#pragma unroll
    for (int k = 0; k < 128; ++k)
        a[k] = Aw[((long)l * 128 + k) * 128 + h];

    const float ab = Ab[l * 128 + h];
    const float th = thr[h];
    const float dc = dec[h];
    const float rs = rstv[h];

    float mem = mem0[((long)l * 256 + b) * 128 + h];
    float spk = 0.f;
    float cnt = 0.f;

    const bool last = (l == 3);
    float* __restrict__ om = omem + (long)b * 301 * 128 + h;
    float* __restrict__ os = ospk + (long)b * 301 * 128 + h;
    if (last) { om[0] = mem; os[0] = 0.f; }

    const float* __restrict__ ip = inp + (long)b * 300 * 128;

    for (int t = 0; t < 300; ++t) {
        float acc = ab;
#pragma unroll
        for (int k = 0; k < 128; ++k)
            acc = fmaf(ip[k], a[k], acc);
        ip += 128;

        mem = rs * spk + mem * dc * (1.f - spk) + acc;
        spk = (mem - th > 0.f) ? 1.f : 0.f;
        cnt += spk;

        if (last) {
            om[(long)(t + 1) * 128] = mem;
            os[(long)(t + 1) * 128] = spk;
        }
    }

    rates[((long)l * 256 + b) * 128 + h] = cnt * (1.f / 300.f);
}

// ---------------------------------------------------------------------------
// K4: head. block per batch row b (256 blocks, 256 threads).
// cat[c] = relu( sum_h rates[l,b,h]*fc_w[l,h,k] + fc_b[l,k] ), c = l*128+k
// out[b,o] = sum_c cat[c]*w_out[c,o] + b_out[o]
// ---------------------------------------------------------------------------
__global__ __launch_bounds__(256)
void k4_head(const float* __restrict__ rates, const float* __restrict__ fcw,
             const float* __restrict__ fcb, const float* __restrict__ wout,
             const float* __restrict__ bout, float* __restrict__ out)
{
    __shared__ float cat[512];
    const int b = blockIdx.x;
    const int tid = threadIdx.x;

    for (int c = tid; c < 512; c += 256) {
        const int l = c >> 7;
        const int k = c & 127;
        float s = fcb[l * 128 + k];
        const float* __restrict__ rp = rates + ((long)l * 256 + b) * 128;
        const float* __restrict__ wp = fcw + (long)l * 128 * 128 + k;
#pragma unroll 8
        for (int hh = 0; hh < 128; ++hh)
            s = fmaf(rp[hh], wp[(long)hh * 128], s);
        cat[c] = s > 0.f ? s : 0.f;
    }
    __syncthreads();

    if (tid < NOUT_) {
        float s = bout[tid];
#pragma unroll 8
        for (int c = 0; c < 512; ++c)
            s = fmaf(cat[c], wout[(long)c * NOUT_ + tid], s);
        out[(long)b * NOUT_ + tid] = s;
    }
}

// ---------------------------------------------------------------------------
// K5: A_norm = sum |A_w| over 4*128*128 elements. Single block.
// ---------------------------------------------------------------------------
__global__ __launch_bounds__(256)
void k5_anorm(const float* __restrict__ Aw, float* __restrict__ out)
{
    __shared__ float red[256];
    const int tid = threadIdx.x;
    float s = 0.f;
    for (int i = tid; i < LL_ * 128 * 128; i += 256)
        s += fabsf(Aw[i]);
    red[tid] = s;
    __syncthreads();
#pragma unroll
    for (int st = 128; st > 0; st >>= 1) {
        if (tid < st) red[tid] += red[tid + st];
        __syncthreads();
    }
    if (tid == 0) out[0] = red[0];
}

// ---------------------------------------------------------------------------
extern "C" void kernel_launch(void* const* d_in, const int* in_sizes, int n_in,
                              void* d_out, int out_size, void* d_ws, size_t ws_size,
                              hipStream_t stream)
{
    const float* x    = (const float*)d_in[0];
    const float* w_in = (const float*)d_in[1];
    const float* b_in = (const float*)d_in[2];
    const float* A_w  = (const float*)d_in[3];
    const float* A_b  = (const float*)d_in[4];
    const float* fc_w = (const float*)d_in[5];
    const float* fc_b = (const float*)d_in[6];
    const float* w_out= (const float*)d_in[7];
    const float* b_out= (const float*)d_in[8];
    const float* thr  = (const float*)d_in[9];
    const float* dec  = (const float*)d_in[10];
    const float* rst  = (const float*)d_in[11];
    const float* mem0 = (const float*)d_in[12];

    float* out  = (float*)d_out;
    float* ws   = (float*)d_ws;
    float* inp   = ws + WS_INP_OFF;     // 76800*128 f32 = 39.3 MB
    float* rates = ws + WS_RATES_OFF;   // 4*256*128 f32

    // K1: input projection GEMM. 76800 rows / 16 per block = 4800 blocks.
    k1_in_proj<<<4800, 128, 0, stream>>>(x, w_in, b_in, inp);

    // K3: fused drive + scan. 4*256 = 1024 blocks (bid = b*4 + l for L2 reuse).
    k3_scan<<<1024, 128, 0, stream>>>(inp, A_w, A_b, thr, dec, rst, mem0,
                                      rates,
                                      out + HMEM_OFF, out + HSPK_OFF);

    // K4: head -> out[256*20]
    k4_head<<<256, 256, 0, stream>>>(rates, fc_w, fc_b, w_out, b_out,
                                     out + OUT_OFF);

    // K5: A_norm (independent of the rest)
    k5_anorm<<<1, 256, 0, stream>>>(A_w, out + ANORM_OFF);
}

// Round 2
// 1379.853 us; speedup vs baseline: 1.2470x; 1.2470x over previous
//
#include <hip/hip_runtime.h>

// Problem dims (fixed)
#define HID_   128
#define BB_    256
#define TT_    300
#define DIN_   700
#define LL_    4
#define NOUT_  20
#define NROWS_ (BB_*TT_)          // 76800

// d_out layout (floats): out[256*20] | hid4_mem[256*301*128] | hid4_spk[...] | A_norm[1]
#define OUT_OFF   0
#define HMEM_OFF  5120
#define HSPK_OFF  (5120 + 256*301*128)            // 9,868,288
#define ANORM_OFF (5120 + 2*256*301*128)          // 19,731,456

// ---------------------------------------------------------------------------
// K1: inp[r][h] = sum_d x[r][d] * w_in[d][h] + b_in[h]
// 128 threads (h), 16 rows/block, K chunked by 28 (700 = 25*28).
// acc[16]+wreg[28] ~= 50 VGPR -> fits 64-reg budget at 8 waves/SIMD.
// x loads are wave-uniform -> scalarized (s_load); w loads coalesced.
// ---------------------------------------------------------------------------
__global__ __launch_bounds__(128, 8)
void k1_in_proj(const float* __restrict__ x, const float* __restrict__ w,
                const float* __restrict__ bin, float* __restrict__ inp)
{
    const int h = threadIdx.x;
    const long r0 = (long)blockIdx.x * 16;

    float acc[16];
    const float bv = bin[h];
#pragma unroll
    for (int r = 0; r < 16; ++r) acc[r] = bv;

    for (int kc = 0; kc < 25; ++kc) {
        const int k0 = kc * 28;
        float wreg[28];
#pragma unroll
        for (int j = 0; j < 28; ++j) wreg[j] = w[(long)(k0 + j) * 128 + h];

#pragma unroll
        for (int r = 0; r < 16; ++r) {
            const float* __restrict__ xr = x + (r0 + r) * (long)DIN_ + k0;
#pragma unroll
            for (int j = 0; j < 28; ++j)
                acc[r] = fmaf(xr[j], wreg[j], acc[r]);
        }
    }

#pragma unroll
    for (int r = 0; r < 16; ++r)
        inp[(r0 + r) * (long)HID_ + h] = acc[r];
}

// ---------------------------------------------------------------------------
// K2: drive GEMM  xs[l][r][h] = sum_k inp[r][k] * A_w[l][k][h] + A_b[l][h]
// lsel >= 0: single layer (grid = 4800 row tiles), xs holds that layer only.
// lsel <  0: all layers  (grid = 19200, l = bx & 3), xs stride lstride rows.
// ---------------------------------------------------------------------------
__global__ __launch_bounds__(128, 8)
void k2_drive(const float* __restrict__ inp, const float* __restrict__ Aw,
              const float* __restrict__ Ab, float* __restrict__ xs,
              int lsel, long lstride)
{
    const int h = threadIdx.x;
    int l, tile;
    if (lsel >= 0) { l = lsel; tile = blockIdx.x; }
    else           { l = blockIdx.x & 3; tile = blockIdx.x >> 2; }
    const long r0 = (long)tile * 16;
    const float* __restrict__ A = Aw + (long)l * 128 * 128;

    float acc[16];
    const float bv = Ab[l * 128 + h];
#pragma unroll
    for (int r = 0; r < 16; ++r) acc[r] = bv;

#pragma unroll
    for (int kc = 0; kc < 4; ++kc) {
        const int k0 = kc * 32;
        float wreg[32];
#pragma unroll
        for (int j = 0; j < 32; ++j) wreg[j] = A[(long)(k0 + j) * 128 + h];

#pragma unroll
        for (int r = 0; r < 16; ++r) {
            const float* __restrict__ xr = inp + (r0 + r) * (long)HID_ + k0;
#pragma unroll
            for (int j = 0; j < 32; ++j)
                acc[r] = fmaf(xr[j], wreg[j], acc[r]);
        }
    }

    float* __restrict__ op = xs + ((long)l * lstride + r0) * HID_ + h;
#pragma unroll
    for (int r = 0; r < 16; ++r)
        op[(long)r * HID_] = acc[r];
}

// ---------------------------------------------------------------------------
// K3': elementwise scan over t. thread = (l,b,h). Batched loads (25 deep)
// keep 25 loads in flight per wave to cover HBM/L2 latency.
// lsel >= 0: grid = 256 (b), layer fixed; xs holds one layer.
// lsel <  0: grid = 1024, l = bid >> 8, b = bid & 255.
// ---------------------------------------------------------------------------
__global__ __launch_bounds__(128, 8)
void k3_scan_split(const float* __restrict__ xs, const float* __restrict__ thr,
                   const float* __restrict__ dec, const float* __restrict__ rstv,
                   const float* __restrict__ mem0, float* __restrict__ rates,
                   float* __restrict__ omem, float* __restrict__ ospk,
                   int lsel, long lstride)
{
    const int h = threadIdx.x;
    int l, b;
    if (lsel >= 0) { l = lsel; b = blockIdx.x; }
    else           { l = blockIdx.x >> 8; b = blockIdx.x & 255; }

    const float th = thr[h];
    const float dc = dec[h];
    const float rs = rstv[h];

    float mem = mem0[((long)l * 256 + b) * 128 + h];
    float spk = 0.f;
    float cnt = 0.f;

    const bool last = (l == 3);
    float* __restrict__ om = omem + (long)b * 301 * 128 + h;
    float* __restrict__ os = ospk + (long)b * 301 * 128 + h;
    if (last) { om[0] = mem; os[0] = 0.f; }

    const float* __restrict__ p = xs + ((long)l * lstride + (long)b * TT_) * HID_ + h;

    for (int t0 = 0; t0 < TT_; t0 += 25) {
        float v[25];
#pragma unroll
        for (int j = 0; j < 25; ++j) v[j] = p[(long)(t0 + j) * HID_];
#pragma unroll
        for (int j = 0; j < 25; ++j) {
            mem = rs * spk + mem * dc * (1.f - spk) + v[j];
            spk = (mem - th > 0.f) ? 1.f : 0.f;
            cnt += spk;
            if (last) {
                om[(long)(t0 + j + 1) * 128] = mem;
                os[(long)(t0 + j + 1) * 128] = spk;
            }
        }
    }

    rates[((long)l * 256 + b) * 128 + h] = cnt * (1.f / 300.f);
}

// ---------------------------------------------------------------------------
// Legacy fused drive+scan (fallback when ws is tiny). Same as round 1.
// ---------------------------------------------------------------------------
__global__ __launch_bounds__(128, 2)
void k3_fused(const float* __restrict__ inp, const float* __restrict__ Aw,
              const float* __restrict__ Ab, const float* __restrict__ thr,
              const float* __restrict__ dec, const float* __restrict__ rstv,
              const float* __restrict__ mem0, float* __restrict__ rates,
              float* __restrict__ omem, float* __restrict__ ospk)
{
    const int h = threadIdx.x;
    const int bid = blockIdx.x;
    const int l = bid & 3;
    const int b = bid >> 2;

    float a[128];
#pragma unroll
    for (int k = 0; k < 128; ++k)
        a[k] = Aw[((long)l * 128 + k) * 128 + h];

    const float ab = Ab[l * 128 + h];
    const float th = thr[h];
    const float dc = dec[h];
    const float rs = rstv[h];

    float mem = mem0[((long)l * 256 + b) * 128 + h];
    float spk = 0.f;
    float cnt = 0.f;

    const bool last = (l == 3);
    float* __restrict__ om = omem + (long)b * 301 * 128 + h;
    float* __restrict__ os = ospk + (long)b * 301 * 128 + h;
    if (last) { om[0] = mem; os[0] = 0.f; }

    const float* __restrict__ ip = inp + (long)b * 300 * 128;

    for (int t = 0; t < 300; ++t) {
        float acc = ab;
#pragma unroll
        for (int k = 0; k < 128; ++k)
            acc = fmaf(ip[k], a[k], acc);
        ip += 128;

        mem = rs * spk + mem * dc * (1.f - spk) + acc;
        spk = (mem - th > 0.f) ? 1.f : 0.f;
        cnt += spk;

        if (last) {
            om[(long)(t + 1) * 128] = mem;
            os[(long)(t + 1) * 128] = spk;
        }
    }

    rates[((long)l * 256 + b) * 128 + h] = cnt * (1.f / 300.f);
}

// ---------------------------------------------------------------------------
// K4: head. block per batch row b.
// ---------------------------------------------------------------------------
__global__ __launch_bounds__(256)
void k4_head(const float* __restrict__ rates, const float* __restrict__ fcw,
             const float* __restrict__ fcb, const float* __restrict__ wout,
             const float* __restrict__ bout, float* __restrict__ out)
{
    __shared__ float cat[512];
    const int b = blockIdx.x;
    const int tid = threadIdx.x;

    for (int c = tid; c < 512; c += 256) {
        const int l = c >> 7;
        const int k = c & 127;
        float s = fcb[l * 128 + k];
        const float* __restrict__ rp = rates + ((long)l * 256 + b) * 128;
        const float* __restrict__ wp = fcw + (long)l * 128 * 128 + k;
#pragma unroll 8
        for (int hh = 0; hh < 128; ++hh)
            s = fmaf(rp[hh], wp[(long)hh * 128], s);
        cat[c] = s > 0.f ? s : 0.f;
    }
    __syncthreads();

    if (tid < NOUT_) {
        float s = bout[tid];
#pragma unroll 8
        for (int c = 0; c < 512; ++c)
            s = fmaf(cat[c], wout[(long)c * NOUT_ + tid], s);
        out[(long)b * NOUT_ + tid] = s;
    }
}

// ---------------------------------------------------------------------------
// K5: A_norm = sum |A_w|. Single block.
// ---------------------------------------------------------------------------
__global__ __launch_bounds__(256)
void k5_anorm(const float* __restrict__ Aw, float* __restrict__ out)
{
    __shared__ float red[256];
    const int tid = threadIdx.x;
    float s = 0.f;
    for (int i = tid; i < LL_ * 128 * 128; i += 256)
        s += fabsf(Aw[i]);
    red[tid] = s;
    __syncthreads();
#pragma unroll
    for (int st = 128; st > 0; st >>= 1) {
        if (tid < st) red[tid] += red[tid + st];
        __syncthreads();
    }
    if (tid == 0) out[0] = red[0];
}

// ---------------------------------------------------------------------------
extern "C" void kernel_launch(void* const* d_in, const int* in_sizes, int n_in,
                              void* d_out, int out_size, void* d_ws, size_t ws_size,
                              hipStream_t stream)
{
    const float* x    = (const float*)d_in[0];
    const float* w_in = (const float*)d_in[1];
    const float* b_in = (const float*)d_in[2];
    const float* A_w  = (const float*)d_in[3];
    const float* A_b  = (const float*)d_in[4];
    const float* fc_w = (const float*)d_in[5];
    const float* fc_b = (const float*)d_in[6];
    const float* w_out= (const float*)d_in[7];
    const float* b_out= (const float*)d_in[8];
    const float* thr  = (const float*)d_in[9];
    const float* dec  = (const float*)d_in[10];
    const float* rst  = (const float*)d_in[11];
    const float* mem0 = (const float*)d_in[12];

    float* out = (float*)d_out;
    float* ws  = (float*)d_ws;

    const long INP_ELTS = (long)NROWS_ * HID_;        //  9,830,400
    const long XS_FULL  = 4L * NROWS_ * HID_;         // 39,321,600
    const long RATES    = 4L * 256 * 128;

    float* inp = ws;                                   // always first

    // K1: input projection. 76800/16 = 4800 blocks.
    k1_in_proj<<<4800, 128, 0, stream>>>(x, w_in, b_in, inp);

    const size_t need_full = (size_t)(INP_ELTS + XS_FULL + RATES) * 4;
    const size_t need_perl = (size_t)(INP_ELTS + INP_ELTS + RATES) * 4;

    if (ws_size >= need_full) {
        float* xs    = ws + INP_ELTS;
        float* rates = xs + XS_FULL;
        k2_drive<<<19200, 128, 0, stream>>>(inp, A_w, A_b, xs, -1, (long)NROWS_);
        k3_scan_split<<<1024, 128, 0, stream>>>(xs, thr, dec, rst, mem0, rates,
                                                out + HMEM_OFF, out + HSPK_OFF,
                                                -1, (long)NROWS_);
        k4_head<<<256, 256, 0, stream>>>(rates, fc_w, fc_b, w_out, b_out, out + OUT_OFF);
    } else if (ws_size >= need_perl) {
        float* xs    = ws + INP_ELTS;
        float* rates = xs + INP_ELTS;
        for (int l = 0; l < 4; ++l) {
            k2_drive<<<4800, 128, 0, stream>>>(inp, A_w, A_b, xs, l, 0L);
            k3_scan_split<<<256, 128, 0, stream>>>(xs, thr, dec, rst, mem0, rates,
                                                   out + HMEM_OFF, out + HSPK_OFF,
                                                   l, 0L);
        }
        k4_head<<<256, 256, 0, stream>>>(rates, fc_w, fc_b, w_out, b_out, out + OUT_OFF);
    } else {
        float* rates = ws + INP_ELTS;
        k3_fused<<<1024, 128, 0, stream>>>(inp, A_w, A_b, thr, dec, rst, mem0,
                                           rates, out + HMEM_OFF, out + HSPK_OFF);
        k4_head<<<256, 256, 0, stream>>>(rates, fc_w, fc_b, w_out, b_out, out + OUT_OFF);
    }

    // K5: A_norm (independent)
    k5_anorm<<<1, 256, 0, stream>>>(A_w, out + ANORM_OFF);
}